// Round 6
// baseline (193.224 us; speedup 1.0000x reference)
//
#include <hip/hip_runtime.h>
#include <hip/hip_bf16.h>

#define NN 100000
#define NE 1000000
#define HD 64
#define NB 98                 // dst buckets of 1024 nodes
#define BSH 10
#define BCAP 12288            // bin capacity (avg 10240, +20 sigma)
#define EPB 8192              // edges per k_bin block
#define NB1 ((NE + EPB - 1) / EPB)   // 123
#define DUMMYB (NN << 7)      // dummy bf16 row byte offset

typedef unsigned short u16;
typedef unsigned int u32;
typedef unsigned long long u64;

__device__ __forceinline__ u16 f2b(float f) {
    __hip_bfloat16 h = __float2bfloat16(f);   // RNE
    return *reinterpret_cast<u16*>(&h);
}
__device__ __forceinline__ float uaf(u32 u) { return __uint_as_float(u); }

// ---------------- CSR build: bucketed counting sort ----------------

__global__ __launch_bounds__(256) void k_bin(const int* __restrict__ ei,
                                             int* __restrict__ bfill,
                                             u64* __restrict__ bins) {
    __shared__ int hist[NB];
    __shared__ int base[NB];
    int tid = threadIdx.x;
    for (int i = tid; i < NB; i += 256) hist[i] = 0;
    __syncthreads();
    int e0 = blockIdx.x * EPB;
    int n = min(EPB, NE - e0);
    for (int i = tid; i < n; i += 256)
        atomicAdd(&hist[ei[NE + e0 + i] >> BSH], 1);
    __syncthreads();
    for (int i = tid; i < NB; i += 256) {
        int c = hist[i];
        base[i] = c ? atomicAdd(&bfill[i], c) : 0;
        hist[i] = 0;
    }
    __syncthreads();
    for (int i = tid; i < n; i += 256) {
        int s = ei[e0 + i];
        int d = ei[NE + e0 + i];
        int g = d >> BSH;
        int pos = base[g] + atomicAdd(&hist[g], 1);
        bins[(size_t)g * BCAP + min(pos, BCAP - 1)] = ((u64)(u32)d << 32) | (u32)s;
    }
}

__global__ __launch_bounds__(256) void k_btot(const u64* __restrict__ bins,
                                              const int* __restrict__ bfill,
                                              int* __restrict__ btot) {
    __shared__ int cnt[1024];
    __shared__ int wtot[4];
    int g = blockIdx.x, tid = threadIdx.x;
    for (int i = tid; i < 1024; i += 256) cnt[i] = 0;
    __syncthreads();
    int n = min(bfill[g], BCAP);
    const u64* bp = bins + (size_t)g * BCAP;
    for (int i = tid; i < n; i += 256)
        atomicAdd(&cnt[(int)(bp[i] >> 32) & 1023], 1);
    __syncthreads();
    int part = 0;
    for (int i = tid; i < 1024; i += 256) {
        int node = (g << BSH) + i;
        if (node < NN) part += (cnt[i] + 8) & ~7;
    }
#pragma unroll
    for (int off = 32; off; off >>= 1) part += __shfl_xor(part, off);
    if ((tid & 63) == 0) wtot[tid >> 6] = part;
    __syncthreads();
    if (tid == 0) btot[g] = wtot[0] + wtot[1] + wtot[2] + wtot[3];
}

__global__ __launch_bounds__(1024) void k_build(const u64* __restrict__ bins,
        const int* __restrict__ bfill, const int* __restrict__ btot,
        int* __restrict__ rowptr, int* __restrict__ col,
        const float2* __restrict__ x2, float* __restrict__ dis,
        float2* __restrict__ xs, u16* __restrict__ hA, u16* __restrict__ hB) {
    __shared__ int cnt[1024];
    __shared__ int rof[1024];
    __shared__ int wsum[16];
    __shared__ int gbase;
    int g = blockIdx.x, tid = threadIdx.x;
    int lane = tid & 63, w = tid >> 6;

    int part = (tid < g) ? btot[tid] : 0;
#pragma unroll
    for (int off = 32; off; off >>= 1) part += __shfl_xor(part, off);
    if (lane == 0) wsum[w] = part;
    cnt[tid] = 0;
    __syncthreads();
    if (tid == 0) {
        int s = 0;
#pragma unroll
        for (int i = 0; i < 16; ++i) s += wsum[i];
        gbase = s;
        if (g == NB - 1) rowptr[NN] = s + btot[g];
    }
    __syncthreads();

    int n = min(bfill[g], BCAP);
    const u64* bp = bins + (size_t)g * BCAP;
    for (int i = tid; i < n; i += 1024)
        atomicAdd(&cnt[(int)(bp[i] >> 32) & 1023], 1);
    __syncthreads();

    int node = (g << BSH) + tid;
    int c = cnt[tid];
    int pc = (node < NN) ? ((c + 8) & ~7) : 0;

    int s = pc;
#pragma unroll
    for (int off = 1; off < 64; off <<= 1) { int t = __shfl_up(s, off); if (lane >= off) s += t; }
    if (lane == 63) wsum[w] = s;
    __syncthreads();
    if (tid < 16) {
        int ws = wsum[tid];
#pragma unroll
        for (int off = 1; off < 16; off <<= 1) { int t = __shfl_up(ws, off); if (tid >= off) ws += t; }
        wsum[tid] = ws;
    }
    __syncthreads();
    int r = gbase + (w ? wsum[w - 1] : 0) + s - pc;
    rof[tid] = r;
    if (node < NN) {
        rowptr[node] = r;
        col[r] = node << 7;                               // self-loop slot 0
        for (int t = c + 1; t < pc; ++t) col[r + t] = DUMMYB;
        float dd = rsqrtf((float)(c + 1));
        dis[node] = dd;
        float2 xv = x2[node];
        xs[node] = make_float2(xv.x * dd, xv.y * dd);
    }
    cnt[tid] = 1;                                         // fill counter (slot 0 taken)
    __syncthreads();

    for (int i = tid; i < n; i += 1024) {
        u64 e = bp[i];
        int d = (int)(e >> 32) & 1023;
        int src = (int)(e & 0xffffffffu);
        int local = atomicAdd(&cnt[d], 1);
        col[rof[d] + local] = src << 7;
    }

    if (g == 0) {
        if (tid < HD) { hA[NN * HD + tid] = 0; hB[NN * HD + tid] = 0; }
        if (tid == 0) xs[NN] = make_float2(0.f, 0.f);
    }
}

// ---------------- fused layers ----------------
// invariant: stored rows pre-scaled by dis[src]; agg scaled by dis[d];
// non-last layers store bf16( relu(agg@W+b) * dis[node] )

__global__ __launch_bounds__(256) void k_layer1(const float2* __restrict__ xs,
        const int* __restrict__ rowptr, const int* __restrict__ col,
        const float* __restrict__ dis, const float* __restrict__ W1,
        const float* __restrict__ b1, u16* __restrict__ hout) {
    int tid = threadIdx.x, lane = tid & 63, wv = tid >> 6;
    int node = blockIdx.x * 4 + wv;
    if (node >= NN) return;
    int s = rowptr[node], e = rowptr[node + 1];
    float ax = 0.f, ay = 0.f;
    for (int base = s; base < e; base += 64) {
        int idx = base + lane;
        int cv = (idx < e) ? col[idx] : DUMMYB;           // pads/dummy add 0
        float2 xv = *(const float2*)((const char*)xs + (size_t)((u32)cv >> 4));
        ax += xv.x; ay += xv.y;
    }
#pragma unroll
    for (int off = 32; off; off >>= 1) { ax += __shfl_xor(ax, off); ay += __shfl_xor(ay, off); }
    float dd = dis[node];
    ax *= dd; ay *= dd;
    float o = fmaxf(fmaf(ax, W1[lane], fmaf(ay, W1[HD + lane], b1[lane])), 0.f);
    hout[node * HD + lane] = f2b(o * dd);
}

// layers 2/3: 4 nodes per wave; each VMEM instruction gathers FOUR rows
// (lane l: dwordx2 = 4 features of row slot l>>4). Col offsets fetched by
// 16-lane broadcast load (no readlanes). Slot partials combined by shfl_xor.
template <bool LAST>
__global__ __launch_bounds__(256) void k_layer(const u16* __restrict__ hin,
        const int* __restrict__ rowptr, const int* __restrict__ col,
        const float* __restrict__ dis, const float* __restrict__ W,
        const float* __restrict__ b, const float* __restrict__ Wl,
        const float* __restrict__ bl, u16* __restrict__ hout,
        float* __restrict__ fout) {
    int tid = threadIdx.x, lane = tid & 63, wv = tid >> 6;
    int n0 = (blockIdx.x * 4 + wv) * 4;          // NN % 16 == 0: no tail
    const char* hb = (const char*)hin;
    int sl  = lane >> 4;                          // row slot 0..3
    int lo8 = (lane & 15) * 8;                    // byte offset within row

    float acc[4][4];
#pragma unroll
    for (int q = 0; q < 4; ++q)
#pragma unroll
        for (int j = 0; j < 4; ++j) acc[q][j] = 0.f;
    float dsv[4];

#pragma unroll
    for (int q = 0; q < 4; ++q) {
        int node = n0 + q;
        int s = rowptr[node], e = rowptr[node + 1];   // padded to x8
        for (int base = s; base < e; base += 8) {
            int cA = col[base + sl];                  // broadcast x16 lanes
            int cB = col[base + 4 + sl];
            uint2 vA = *(const uint2*)(hb + cA + lo8);   // 4 rows / instr
            uint2 vB = *(const uint2*)(hb + cB + lo8);
            acc[q][0] += uaf(vA.x << 16);
            acc[q][1] += uaf(vA.x & 0xffff0000u);
            acc[q][2] += uaf(vA.y << 16);
            acc[q][3] += uaf(vA.y & 0xffff0000u);
            acc[q][0] += uaf(vB.x << 16);
            acc[q][1] += uaf(vB.x & 0xffff0000u);
            acc[q][2] += uaf(vB.y << 16);
            acc[q][3] += uaf(vB.y & 0xffff0000u);
        }
        float dd = dis[node];
        dsv[q] = dd;
#pragma unroll
        for (int j = 0; j < 4; ++j) {                 // combine 4 slot groups
            float v = acc[q][j];
            v += __shfl_xor(v, 16);
            v += __shfl_xor(v, 32);
            acc[q][j] = v * dd;
        }
    }

    // transform: feature k lives in acc[q][k&3], lane k>>2
    float bb = b[lane];
    float o[4] = {bb, bb, bb, bb};
#pragma unroll
    for (int k = 0; k < HD; ++k) {
        float w = W[k * HD + lane];                   // one load feeds 4 nodes
#pragma unroll
        for (int q = 0; q < 4; ++q) {
            float a = __int_as_float(
                __builtin_amdgcn_readlane(__float_as_int(acc[q][k & 3]), k >> 2));
            o[q] = fmaf(a, w, o[q]);
        }
    }

    if (!LAST) {
#pragma unroll
        for (int q = 0; q < 4; ++q)
            hout[(n0 + q) * HD + lane] = f2b(fmaxf(o[q], 0.f) * dsv[q]);
    } else {
        float wl = Wl[lane];
        float r0, r1, r2, r3;
#pragma unroll
        for (int q = 0; q < 4; ++q) {
            float v = fmaxf(o[q], 0.f) * wl;
#pragma unroll
            for (int off = 32; off; off >>= 1) v += __shfl_xor(v, off);
            if (q == 0) r0 = v; else if (q == 1) r1 = v; else if (q == 2) r2 = v; else r3 = v;
        }
        float r = (lane == 0) ? r0 : (lane == 1) ? r1 : (lane == 2) ? r2 : r3;
        if (lane < 4) fout[n0 + lane] = r + bl[0];
    }
}

// ---------------- launch ----------------

extern "C" void kernel_launch(void* const* d_in, const int* in_sizes, int n_in,
                              void* d_out, int out_size, void* d_ws, size_t ws_size,
                              hipStream_t stream) {
    const float* x  = (const float*)d_in[0];
    const int*   ei = (const int*)d_in[1];   // [2,E]: src = ei[0:E], dst = ei[E:2E]
    const float* W1 = (const float*)d_in[2];
    const float* b1 = (const float*)d_in[3];
    const float* W2 = (const float*)d_in[4];
    const float* b2 = (const float*)d_in[5];
    const float* W3 = (const float*)d_in[6];
    const float* b3 = (const float*)d_in[7];
    const float* Wl = (const float*)d_in[8];
    const float* bl = (const float*)d_in[9];

    // workspace layout (bins first: u64-aligned)
    u64*    bins   = (u64*)d_ws;                       // NB*BCAP u64   (9.6 MB)
    float2* xs     = (float2*)(bins + (size_t)NB * BCAP); // NN+1
    int*    bfill  = (int*)(xs + (NN + 1));            // NB (pad 128)
    int*    btot   = bfill + 128;                      // NB (pad 128)
    int*    rowptr = btot + 128;                       // NN+1 (+1 pad)
    float*  dis    = (float*)(rowptr + (NN + 2));      // NN
    int*    col    = (int*)(dis + NN);                 // NE + 8*NN + 64 overread pad
    u16*    hA     = (u16*)(col + (NE + 8 * NN + 64)); // (NN+1)*HD bf16
    u16*    hB     = hA + (size_t)(NN + 1) * HD;       // (NN+1)*HD bf16

    hipMemsetAsync(bfill, 0, NB * sizeof(int), stream);
    k_bin  <<<NB1, 256, 0, stream>>>(ei, bfill, bins);
    k_btot <<<NB, 256, 0, stream>>>(bins, bfill, btot);
    k_build<<<NB, 1024, 0, stream>>>(bins, bfill, btot, rowptr, col,
                                     (const float2*)x, dis, xs, hA, hB);

    k_layer1<<<(NN + 3) / 4, 256, 0, stream>>>(xs, rowptr, col, dis, W1, b1, hA);
    k_layer<false><<<NN / 16, 256, 0, stream>>>(hA, rowptr, col, dis, W2, b2,
                                                nullptr, nullptr, hB, nullptr);
    k_layer<true ><<<NN / 16, 256, 0, stream>>>(hB, rowptr, col, dis, W3, b3,
                                                Wl, bl, nullptr, (float*)d_out);
}